// Round 8
// baseline (176.013 us; speedup 1.0000x reference)
//
#include <hip/hip_runtime.h>
#include <hip/hip_fp16.h>
#include <math.h>
#include <string.h>

#define HH 32
#define WW 32
#define HWSZ 1024      // H*W
#define CC 384
#define NHEAD 12
#define NGROUP 6
#define HC 32
#define GC 64
#define NS 1024        // n_sample
#define ATTN_SCALE 0.17677669529663687f  // 32^-0.5

typedef _Float16 half8_t __attribute__((ext_vector_type(8)));
typedef _Float16 half4_t __attribute__((ext_vector_type(4)));
typedef _Float16 half2_t __attribute__((ext_vector_type(2)));
typedef float    f4_t    __attribute__((ext_vector_type(4)));

// ---------------------------------------------------------------------------
// R21 MFMA GEMM: Y = W·X + b. 32m x 32n tile, BK=32, grid (32,12,2)=768
// blocks -> 3 blocks/CU. Register prefetch of next K-tile between barriers.
// W pure f16; X pure f16 (XLO=0, q-proj) or f16 hi/lo (XLO=1, o-proj).
// ---------------------------------------------------------------------------
template<int XLO>
__global__ __launch_bounds__(256) void gemm_wx(
    const float* __restrict__ W, const float* __restrict__ bias,
    const float* __restrict__ X, float* __restrict__ Y)
{
    const int bz = blockIdx.z;
    const int tm = blockIdx.y * 32;
    const int tn = blockIdx.x * 32;
    const int tid = threadIdx.x;
    const int w = tid >> 6, lane = tid & 63;
    const int quad = lane >> 4, lcol = lane & 15;
    const int wr = w >> 1, wc = w & 1;       // wave's output quadrant

    __shared__ _Float16 sW[32][40];
    __shared__ _Float16 sX[32][40];
    __shared__ _Float16 sXl[XLO ? 32 : 1][40];

    const float* Xb = X + (size_t)bz * CC * 1024;
    float* Yb = Y + (size_t)bz * CC * 1024;

    const int m  = tid >> 3;
    const int j4 = (tid & 7) * 4;

    float4 wv = *(const float4*)&W[(size_t)(tm + m) * CC + j4];
    float4 xv = *(const float4*)&Xb[(size_t)m * 1024 + tn + j4];

    f4_t acc = {0.f, 0.f, 0.f, 0.f};

#pragma unroll 1
    for (int k0 = 0; k0 < CC; k0 += 32) {
        {
            half4_t hw; hw[0] = (_Float16)wv.x; hw[1] = (_Float16)wv.y;
            hw[2] = (_Float16)wv.z; hw[3] = (_Float16)wv.w;
            *(half4_t*)&sW[m][j4] = hw;
#pragma unroll
            for (int i = 0; i < 4; ++i) {
                float v = (i == 0) ? xv.x : (i == 1) ? xv.y : (i == 2) ? xv.z : xv.w;
                _Float16 h = (_Float16)v;
                sX[j4 + i][m] = h;
                if (XLO) sXl[j4 + i][m] = (_Float16)(v - (float)h);
            }
        }
        __syncthreads();

        if (k0 + 32 < CC) {
            wv = *(const float4*)&W[(size_t)(tm + m) * CC + k0 + 32 + j4];
            xv = *(const float4*)&Xb[(size_t)(k0 + 32 + m) * 1024 + tn + j4];
        }

        half8_t A = *(const half8_t*)&sW[wr * 16 + lcol][quad * 8];
        half8_t B = *(const half8_t*)&sX[wc * 16 + lcol][quad * 8];
        acc = __builtin_amdgcn_mfma_f32_16x16x32_f16(A, B, acc, 0, 0, 0);
        if (XLO) {
            half8_t Bl = *(const half8_t*)&sXl[wc * 16 + lcol][quad * 8];
            acc = __builtin_amdgcn_mfma_f32_16x16x32_f16(A, Bl, acc, 0, 0, 0);
        }
        __syncthreads();
    }

#pragma unroll
    for (int r = 0; r < 4; ++r) {
        int m0 = tm + wr * 16 + quad * 4 + r;
        Yb[(size_t)m0 * 1024 + tn + wc * 16 + lcol] = acc[r] + bias[m0];
    }
}

// ---------------------------------------------------------------------------
// R21 FUSED MFMA K+V projection, 32n tiles, grid (32,12,2)=768 blocks.
// ---------------------------------------------------------------------------
__global__ __launch_bounds__(256) void gemm_kv_fused(
    const float* __restrict__ Wk, const float* __restrict__ bk,
    const float* __restrict__ Wv, const float* __restrict__ bv,
    const _Float16* __restrict__ X,
    _Float16* __restrict__ khT, _Float16* __restrict__ vhb)
{
    const int bz = blockIdx.z;
    const int head = blockIdx.y;
    const int tm = head * 32;
    const int tn = blockIdx.x * 32;
    const int tid = threadIdx.x;
    const int w = tid >> 6, lane = tid & 63;
    const int quad = lane >> 4, lcol = lane & 15;
    const int bh = bz * 12 + head;
    const int nt = w & 1;

    __shared__ _Float16 sWk[32][40], sWv[32][40];
    __shared__ _Float16 sX[32][40];

    const _Float16* Xb = X + (size_t)bz * CC * 1024;

    const int m  = tid >> 3;
    const int j4 = (tid & 7) * 4;

    float4 wkv = *(const float4*)&Wk[(size_t)(tm + m) * CC + j4];
    float4 wvv = *(const float4*)&Wv[(size_t)(tm + m) * CC + j4];
    half4_t xh = *(const half4_t*)&Xb[(size_t)m * 1024 + tn + j4];

    f4_t a0 = {0.f, 0.f, 0.f, 0.f}, a1 = {0.f, 0.f, 0.f, 0.f};

#pragma unroll 1
    for (int k0 = 0; k0 < CC; k0 += 32) {
        {
            half4_t hk; hk[0] = (_Float16)wkv.x; hk[1] = (_Float16)wkv.y;
            hk[2] = (_Float16)wkv.z; hk[3] = (_Float16)wkv.w;
            half4_t hv; hv[0] = (_Float16)wvv.x; hv[1] = (_Float16)wvv.y;
            hv[2] = (_Float16)wvv.z; hv[3] = (_Float16)wvv.w;
            *(half4_t*)&sWk[m][j4] = hk;
            *(half4_t*)&sWv[m][j4] = hv;
#pragma unroll
            for (int i = 0; i < 4; ++i)
                sX[j4 + i][m] = xh[i];
        }
        __syncthreads();

        if (k0 + 32 < CC) {
            wkv = *(const float4*)&Wk[(size_t)(tm + m) * CC + k0 + 32 + j4];
            wvv = *(const float4*)&Wv[(size_t)(tm + m) * CC + k0 + 32 + j4];
            xh  = *(const half4_t*)&Xb[(size_t)(k0 + 32 + m) * 1024 + tn + j4];
        }

        half8_t Xa = *(const half8_t*)&sX[nt * 16 + lcol][quad * 8];
        if (w < 2) {
            half8_t K0 = *(const half8_t*)&sWk[lcol][quad * 8];
            half8_t K1 = *(const half8_t*)&sWk[16 + lcol][quad * 8];
            a0 = __builtin_amdgcn_mfma_f32_16x16x32_f16(Xa, K0, a0, 0, 0, 0);
            a1 = __builtin_amdgcn_mfma_f32_16x16x32_f16(Xa, K1, a1, 0, 0, 0);
        } else {
            half8_t V0 = *(const half8_t*)&sWv[lcol][quad * 8];
            half8_t V1 = *(const half8_t*)&sWv[16 + lcol][quad * 8];
            a0 = __builtin_amdgcn_mfma_f32_16x16x32_f16(V0, Xa, a0, 0, 0, 0);
            a1 = __builtin_amdgcn_mfma_f32_16x16x32_f16(V1, Xa, a1, 0, 0, 0);
        }
        __syncthreads();
    }

    if (w < 2) {
        float bk0 = bk[tm + lcol], bk1 = bk[tm + 16 + lcol];
#pragma unroll
        for (int r = 0; r < 4; ++r) {
            int n = tn + nt * 16 + quad * 4 + r;
            khT[((size_t)bh * 1024 + n) * 32 + lcol]      = (_Float16)(a0[r] + bk0);
            khT[((size_t)bh * 1024 + n) * 32 + 16 + lcol] = (_Float16)(a1[r] + bk1);
        }
    } else {
#pragma unroll
        for (int r = 0; r < 4; ++r) {
            int hc0 = quad * 4 + r;
            vhb[((size_t)bh * 32 + hc0) * 1024 + tn + nt * 16 + lcol] =
                (_Float16)(a0[r] + bv[tm + hc0]);
            vhb[((size_t)bh * 32 + hc0 + 16) * 1024 + tn + nt * 16 + lcol] =
                (_Float16)(a1[r] + bv[tm + hc0 + 16]);
        }
    }
}

// ---------------------------------------------------------------------------
// Depthwise 7x7 conv, zero pad 3 (unchanged).
// ---------------------------------------------------------------------------
__global__ __launch_bounds__(256) void dwconv_kernel(
    const float* __restrict__ q, const float* __restrict__ dww,
    const float* __restrict__ dwb, float* __restrict__ oconv)
{
    const int bc = blockIdx.x;
    const int bg = bc >> 6, c = bc & 63;
    const int b = bg / 6, g = bg % 6;
    const float* plane = q + ((size_t)b * CC + g * 64 + c) * 1024;

    __shared__ float sp[1024];
    __shared__ float sw[49];
    const int tid = threadIdx.x;
    for (int i = tid; i < 1024; i += 256) sp[i] = plane[i];
    if (tid < 49) sw[tid] = dww[c * 49 + tid];
    __syncthreads();

    const float bias = dwb[c];
    for (int i = tid; i < 1024; i += 256) {
        int y = i >> 5, x = i & 31;
        float s = 0.f;
#pragma unroll
        for (int ky = 0; ky < 7; ++ky) {
            int yy = y + ky - 3;
            if (yy < 0 || yy > 31) continue;
#pragma unroll
            for (int kx = 0; kx < 7; ++kx) {
                int xx = x + kx - 3;
                if (xx < 0 || xx > 31) continue;
                s += sp[yy * 32 + xx] * sw[ky * 7 + kx];
            }
        }
        oconv[(size_t)bc * 1024 + i] = s + bias;
    }
}

// ---------------------------------------------------------------------------
// R22: LN + GELU + pw + tanh once per pixel -> pos, then gather all 64 ch
// -> xs (f16). 32 px x 8 ch-groups per block, grid (32,12)=384 blocks.
// ---------------------------------------------------------------------------
__global__ __launch_bounds__(256) void offset_sample_once_kernel(
    const float* __restrict__ oconv, const float* __restrict__ lng,
    const float* __restrict__ lnb, const float* __restrict__ pw,
    const float* __restrict__ x, float* __restrict__ pos,
    _Float16* __restrict__ xs)
{
    const int bg = blockIdx.y;
    const int px0 = blockIdx.x * 32;
    const int t = threadIdx.x;
    const int cg = t >> 5;          // 0..7 channel group (8 ch each)
    const int pl = t & 31;          // 0..31 pixel
    const int px = px0 + pl;
    const int b = bg / 6, g = bg % 6;

    __shared__ float red[8][32];
    __shared__ float spos[32][2];

    const float* base = oconv + ((size_t)bg * 64 + cg * 8) * 1024 + px;
    float col[8];
    float s = 0.f;
#pragma unroll
    for (int i = 0; i < 8; ++i) { col[i] = base[(size_t)i * 1024]; s += col[i]; }
    red[cg][pl] = s;
    __syncthreads();
    float mu = 0.f;
#pragma unroll
    for (int j = 0; j < 8; ++j) mu += red[j][pl];
    mu *= (1.f / 64.f);
    float v = 0.f;
#pragma unroll
    for (int i = 0; i < 8; ++i) { float d = col[i] - mu; v += d * d; }
    __syncthreads();
    red[cg][pl] = v;
    __syncthreads();
    float vs = 0.f;
#pragma unroll
    for (int j = 0; j < 8; ++j) vs += red[j][pl];
    float inv = rsqrtf(vs * (1.f / 64.f) + 1e-5f);

    float oy = 0.f, ox = 0.f;
#pragma unroll
    for (int i = 0; i < 8; ++i) {
        int c = cg * 8 + i;
        float val = (col[i] - mu) * inv * lng[c] + lnb[c];
        float gl = 0.5f * val * (1.f + erff(val * 0.70710678118654752440f));
        oy += gl * pw[c];
        ox += gl * pw[64 + c];
    }
    __syncthreads();
    red[cg][pl] = oy;
    __syncthreads();
    float oyt = 0.f;
#pragma unroll
    for (int j = 0; j < 8; ++j) oyt += red[j][pl];
    __syncthreads();
    red[cg][pl] = ox;
    __syncthreads();
    if (cg == 0) {
        float oxt = 0.f;
#pragma unroll
        for (int j = 0; j < 8; ++j) oxt += red[j][pl];
        float offy = tanhf(oyt) * (2.0f / 32.0f);
        float offx = tanhf(oxt) * (2.0f / 32.0f);
        int y = px >> 5, xx = px & 31;
        float ry = ((y + 0.5f) / 32.f) * 2.f - 1.f;
        float rx = ((xx + 0.5f) / 32.f) * 2.f - 1.f;
        float pyv = offy + ry, pxv = offx + rx;
        spos[pl][0] = pyv; spos[pl][1] = pxv;
        pos[((size_t)bg * 1024 + px) * 2 + 0] = pyv;
        pos[((size_t)bg * 1024 + px) * 2 + 1] = pxv;
    }
    __syncthreads();

    float py = spos[pl][0], pxv = spos[pl][1];
    float gx = (pxv + 1.f) * 0.5f * 31.f;
    float gy = (py + 1.f) * 0.5f * 31.f;
    float x0f = floorf(gx), y0f = floorf(gy);
    float wx = gx - x0f, wy = gy - y0f;
    int x0 = (int)x0f, y0 = (int)y0f;
    float vx0 = ((unsigned)x0 <= 31u) ? 1.f : 0.f;
    float vx1 = ((unsigned)(x0 + 1) <= 31u) ? 1.f : 0.f;
    float vy0 = ((unsigned)y0 <= 31u) ? 1.f : 0.f;
    float vy1 = ((unsigned)(y0 + 1) <= 31u) ? 1.f : 0.f;
    float w00 = (1.f - wx) * (1.f - wy) * vx0 * vy0;
    float w01 = wx * (1.f - wy) * vx1 * vy0;
    float w10 = (1.f - wx) * wy * vx0 * vy1;
    float w11 = wx * wy * vx1 * vy1;
    int xc0 = min(max(x0, 0), 31), xc1 = min(max(x0 + 1, 0), 31);
    int yc0 = min(max(y0, 0), 31), yc1 = min(max(y0 + 1, 0), 31);
    int i00 = yc0 * 32 + xc0, i01 = yc0 * 32 + xc1;
    int i10 = yc1 * 32 + xc0, i11 = yc1 * 32 + xc1;

    const float* xg = x + ((size_t)b * CC + g * 64) * 1024;
    _Float16* xso = xs + ((size_t)b * CC + g * 64) * 1024 + px;
#pragma unroll
    for (int i = 0; i < 8; ++i) {
        int c = cg * 8 + i;
        const float* plane = xg + (size_t)c * 1024;
        xso[(size_t)c * 1024] =
            (_Float16)(plane[i00] * w00 + plane[i01] * w01
                     + plane[i10] * w10 + plane[i11] * w11);
    }
}

// ---------------------------------------------------------------------------
// MFMA flash attention, TWO HEADS PER BLOCK. R23 changes (attn was measured
// at 44.7us, MfmaUtil 2.5 / VALUBusy 22 / Occ 14 -> latency-bound):
//  (a) per-key geometry packed to ONE 8-byte word: {f32 u, f16 wy | i16 iy}.
//      One ds_read_b64 per key (was float2+int = 2 reads); skxy+siy 12KB
//      -> sgeo 8KB. LDS total 42112 -> 38016 < 40KB => 4 blocks/CU
//      (16 waves/CU, was 12). __launch_bounds__(256,4) enforces.
//  (b) hot loop restructured for MLP: per t, load 4 geos -> compute 4 tap
//      addresses -> issue all 16 tap loads -> lerps (4-deep overlap).
// ---------------------------------------------------------------------------
__global__ __launch_bounds__(256, 4) void attn_mfma_kernel(
    const float* __restrict__ q, const _Float16* __restrict__ khT,
    const _Float16* __restrict__ vhb, const float* __restrict__ pos,
    const float* __restrict__ rpe, float* __restrict__ out)
{
    const int bgp = blockIdx.y;            // 0..11 = (b, g)
    const int b = bgp / 6, g = bgp % 6;
    const int h0 = g * 2;
    const int bh0 = b * 12 + h0, bh1 = bh0 + 1;
    const int mblk = blockIdx.x * 16;
    const int tid = threadIdx.x;
    const int w = tid >> 6, lane = tid & 63;
    const int quad = lane >> 4, lcol = lane & 15;

    __shared__ __align__(16) char smem[38016];
    half2_t*  srpeA = (half2_t*)smem;                        // 2205 x {h0,h1}
    _Float16* sqh   = (_Float16*)(smem + 8832);              // 2048B
    _Float16* spw   = (_Float16*)(smem + 10880) + w * 2304;  // P slabs
    float*    comb0 = (float*)(smem + 10880);                // alias P slabs
    float*    comb1 = (float*)(smem + 20096);
    float*    cml0  = (float*)(smem + 29312);
    float*    cml1  = (float*)(smem + 29568);
    float2*   sgeo  = (float2*)(smem + 29824);               // packed geometry

    const float qyw = (((mblk >> 5) + 0.5f) * (1.f / 32.f)) * 2.f - 1.f;
    int r0; {
        float gy_lo = (qyw - 1.03125f) * 15.5f + 31.f;
        r0 = (int)floorf(gy_lo);
        r0 = min(max(r0, 0), 28);
    }

    {   // stage both heads' RPE window, head-interleaved (single table)
        const float* rp0 = rpe + (size_t)h0 * 3969;
        const float* rp1 = rp0 + 3969;
        for (int i = tid; i < 35 * 63; i += 256) {
            int y = i / 63, xx = i - y * 63;
            int gi = (r0 + y) * 63 + xx;
            half2_t hA; hA[0] = (_Float16)rp0[gi]; hA[1] = (_Float16)rp1[gi];
            srpeA[i] = hA;
        }
    }
    {   // stage q (pre-scaled by ATTN_SCALE) for both heads: [head][m][hc]
        const float* qb = q + ((size_t)b * CC + h0 * 32) * 1024 + mblk;
        for (int i = tid; i < 1024; i += 256) {
            int hh = i >> 9, rem = i & 511;
            int hc = rem >> 4, m = rem & 15;
            sqh[hh * 512 + m * 32 + hc] =
                (_Float16)(qb[(size_t)(hh * 32 + hc) * 1024 + m] * ATTN_SCALE);
        }
    }
    {   // per-key packed geometry: {u = 31 - px*15.5, wy f16, iy i16}
        const float2* pgv = (const float2*)(pos + (size_t)bgp * 2048);
        for (int i = tid; i < 1024; i += 256) {
            float2 pp = pgv[i];
            float gy = (qyw - pp.x) * 15.5f + 31.f;
            float y0f = floorf(gy);
            _Float16 wyh = (_Float16)(gy - y0f);
            int iy = ((int)y0f - r0) * 63;
            unsigned short wyb;
            __builtin_memcpy(&wyb, &wyh, 2);
            unsigned pk = ((unsigned)(unsigned short)(short)iy << 16) | wyb;
            sgeo[i] = make_float2(31.f - pp.y * 15.5f, __uint_as_float(pk));
        }
    }
    __syncthreads();

    half8_t qf0 = *(const half8_t*)&sqh[lcol * 32 + quad * 8];
    half8_t qf1 = *(const half8_t*)&sqh[512 + lcol * 32 + quad * 8];
    const float qxs = ((mblk & 31) + lcol + 0.5f) * 0.96875f - 15.5f;  // qx*15.5

    const _Float16* khb0 = khT + (size_t)bh0 * 1024 * 32;
    const _Float16* khb1 = khT + (size_t)bh1 * 1024 * 32;
    const _Float16* vhh0 = vhb + (size_t)bh0 * 32 * 1024;
    const _Float16* vhh1 = vhb + (size_t)bh1 * 32 * 1024;

    f4_t o00 = {0.f, 0.f, 0.f, 0.f}, o01 = {0.f, 0.f, 0.f, 0.f};
    f4_t o10 = {0.f, 0.f, 0.f, 0.f}, o11 = {0.f, 0.f, 0.f, 0.f};
    float lsum0 = 0.f, lsum1 = 0.f;

    half8_t kA0[4], kA1[4], kB0[4], kB1[4];

    auto loadK = [&](half8_t* d0, half8_t* d1, int cc) {
        int nn = w * 256 + cc * 64;
#pragma unroll
        for (int t = 0; t < 4; ++t) {
            size_t off = (size_t)(nn + t * 16 + lcol) * 32 + quad * 8;
            d0[t] = *(const half8_t*)&khb0[off];
            d1[t] = *(const half8_t*)&khb1[off];
        }
    };

    auto computeC = [&](const half8_t* kh0, const half8_t* kh1, int c) {
        const int n0 = w * 256 + c * 64;

        f4_t S0[4], S1[4];
#pragma unroll
        for (int t = 0; t < 4; ++t) {
            f4_t s0 = {0.f, 0.f, 0.f, 0.f}, s1 = {0.f, 0.f, 0.f, 0.f};
            s0 = __builtin_amdgcn_mfma_f32_16x16x32_f16(kh0[t], qf0, s0, 0, 0, 0);
            s1 = __builtin_amdgcn_mfma_f32_16x16x32_f16(kh1[t], qf1, s1, 0, 0, 0);

            // (1) load 4 keys' packed geometry (one b64 each, broadcast)
            float2 gg[4];
#pragma unroll
            for (int r = 0; r < 4; ++r)
                gg[r] = sgeo[n0 + t * 16 + quad * 4 + r];

            // (2) compute all tap addresses + weights
            int i00[4];
            _Float16 wxv[4], wyv[4];
#pragma unroll
            for (int r = 0; r < 4; ++r) {
                float gx = qxs + gg[r].x;
                float x0f = floorf(gx);
                unsigned pk = __float_as_uint(gg[r].y);
                i00[r] = (int)(short)(pk >> 16) + (int)x0f;
                wxv[r] = (_Float16)(gx - x0f);
                unsigned short wyb = (unsigned short)(pk & 0xFFFFu);
                __builtin_memcpy(&wyv[r], &wyb, 2);
            }

            // (3) issue all 16 tap loads (4-deep MLP)
            half2_t a0[4], b0[4], a1[4], b1[4];
#pragma unroll
            for (int r = 0; r < 4; ++r) {
                a0[r] = srpeA[i00[r]];
                b0[r] = srpeA[i00[r] + 1];
                a1[r] = srpeA[i00[r] + 63];
                b1[r] = srpeA[i00[r] + 64];
            }

            // (4) packed lerps
#pragma unroll
            for (int r = 0; r < 4; ++r) {
                half2_t wxh; wxh[0] = wxv[r]; wxh[1] = wxv[r];
                half2_t wyh; wyh[0] = wyv[r]; wyh[1] = wyv[r];
                half2_t top = a0[r] + (b0[r] - a0[r]) * wxh;
                half2_t bot = a1[r] + (b1[r] - a1[r]) * wxh;
                half2_t res = top + (bot - top) * wyh;
                s0[r] = s0[r] + (float)res[0];    // scale pre-folded into q
                s1[r] = s1[r] + (float)res[1];
            }
            S0[t] = s0; S1[t] = s1;
        }

        // prefetch V for head0 (covers exp-section latency)
        half8_t vv00[2], vv01[2];
#pragma unroll
        for (int kp = 0; kp < 2; ++kp) {
            int nb = n0 + kp * 32 + quad * 8;
            vv00[kp] = *(const half8_t*)&vhh0[(size_t)lcol * 1024 + nb];
            vv01[kp] = *(const half8_t*)&vhh0[(size_t)(16 + lcol) * 1024 + nb];
        }

        // fixed-shift exp + P stores for both heads
#pragma unroll
        for (int t = 0; t < 4; ++t) {
            float p0 = __expf(S0[t][0]), p1 = __expf(S0[t][1]);
            float p2 = __expf(S0[t][2]), p3 = __expf(S0[t][3]);
            lsum0 += (p0 + p1) + (p2 + p3);
            half4_t h;
            h[0] = (_Float16)p0; h[1] = (_Float16)p1;
            h[2] = (_Float16)p2; h[3] = (_Float16)p3;
            *(half4_t*)&spw[lcol * 72 + t * 16 + quad * 4] = h;
            float r0e = __expf(S1[t][0]), r1e = __expf(S1[t][1]);
            float r2e = __expf(S1[t][2]), r3e = __expf(S1[t][3]);
            lsum1 += (r0e + r1e) + (r2e + r3e);
            half4_t h1;
            h1[0] = (_Float16)r0e; h1[1] = (_Float16)r1e;
            h1[2] = (_Float16)r2e; h1[3] = (_Float16)r3e;
            *(half4_t*)&spw[1152 + lcol * 72 + t * 16 + quad * 4] = h1;
        }

        // PV head0 (wave-internal LDS read-back; no barrier)
#pragma unroll
        for (int kp = 0; kp < 2; ++kp) {
            half8_t pb = *(const half8_t*)&spw[lcol * 72 + kp * 32 + quad * 8];
            o00 = __builtin_amdgcn_mfma_f32_16x16x32_f16(vv00[kp], pb, o00, 0, 0, 0);
            o01 = __builtin_amdgcn_mfma_f32_16x16x32_f16(vv01[kp], pb, o01, 0, 0, 0);
        }
        // PV head1 (V loaded JIT)
#pragma unroll
        for (int kp = 0; kp < 2; ++kp) {
            int nb = n0 + kp * 32 + quad * 8;
            half8_t v0 = *(const half8_t*)&vhh1[(size_t)lcol * 1024 + nb];
            half8_t v1 = *(const half8_t*)&vhh1[(size_t)(16 + lcol) * 1024 + nb];
            half8_t pb = *(const half8_t*)&spw[1152 + lcol * 72 + kp * 32 + quad * 8];
            o10 = __builtin_amdgcn_mfma_f32_16x16x32_f16(v0, pb, o10, 0, 0, 0);
            o11 = __builtin_amdgcn_mfma_f32_16x16x32_f16(v1, pb, o11, 0, 0, 0);
        }
    };

    loadK(kA0, kA1, 0);
#pragma unroll 1
    for (int it = 0; it < 2; ++it) {
        int c = it * 2;
        loadK(kB0, kB1, c + 1);          // prefetch c+1 before computing c
        computeC(kA0, kA1, c);
        if (it == 0) loadK(kA0, kA1, c + 2);
        computeC(kB0, kB1, c + 1);
    }

    lsum0 += __shfl_xor(lsum0, 16); lsum0 += __shfl_xor(lsum0, 32);
    lsum1 += __shfl_xor(lsum1, 16); lsum1 += __shfl_xor(lsum1, 32);

    __syncthreads();   // all waves done with P slabs -> alias as comb0/comb1

    *(f4_t*)&comb0[(w * 16 + lcol) * 36 + quad * 4]      = o00;
    *(f4_t*)&comb0[(w * 16 + lcol) * 36 + 16 + quad * 4] = o01;
    *(f4_t*)&comb1[(w * 16 + lcol) * 36 + quad * 4]      = o10;
    *(f4_t*)&comb1[(w * 16 + lcol) * 36 + 16 + quad * 4] = o11;
    if (quad == 0) {
        cml0[w * 16 + lcol] = lsum0;
        cml1[w * 16 + lcol] = lsum1;
    }
    __syncthreads();

#pragma unroll
    for (int i = 0; i < 2; ++i) {
        int idx = tid + i * 256;
        int qq = idx >> 5, hc = idx & 31;
        {
            float L = cml0[qq] + cml0[16 + qq] + cml0[32 + qq] + cml0[48 + qq];
            float o = comb0[(0 * 16 + qq) * 36 + hc]
                    + comb0[(1 * 16 + qq) * 36 + hc]
                    + comb0[(2 * 16 + qq) * 36 + hc]
                    + comb0[(3 * 16 + qq) * 36 + hc];
            out[((size_t)b * CC + h0 * 32 + hc) * 1024 + mblk + qq] = o / L;
        }
        {
            float L = cml1[qq] + cml1[16 + qq] + cml1[32 + qq] + cml1[48 + qq];
            float o = comb1[(0 * 16 + qq) * 36 + hc]
                    + comb1[(1 * 16 + qq) * 36 + hc]
                    + comb1[(2 * 16 + qq) * 36 + hc]
                    + comb1[(3 * 16 + qq) * 36 + hc];
            out[((size_t)b * CC + (h0 + 1) * 32 + hc) * 1024 + mblk + qq] = o / L;
        }
    }
}

// ---------------------------------------------------------------------------
extern "C" void kernel_launch(void* const* d_in, const int* in_sizes, int n_in,
                              void* d_out, int out_size, void* d_ws, size_t ws_size,
                              hipStream_t stream) {
    const float* x   = (const float*)d_in[0];
    const float* Wq  = (const float*)d_in[1];
    const float* bq  = (const float*)d_in[2];
    const float* Wk  = (const float*)d_in[3];
    const float* bk  = (const float*)d_in[4];
    const float* Wv  = (const float*)d_in[5];
    const float* bv  = (const float*)d_in[6];
    const float* Wo  = (const float*)d_in[7];
    const float* bo  = (const float*)d_in[8];
    const float* dww = (const float*)d_in[9];
    const float* dwb = (const float*)d_in[10];
    const float* lng = (const float*)d_in[11];
    const float* lnb = (const float*)d_in[12];
    const float* pw  = (const float*)d_in[13];
    const float* rpe = (const float*)d_in[14];

    float* ws = (float*)d_ws;
    const size_t SZ = 786432;           // 2*384*1024 floats
    float* qbuf  = ws;
    _Float16* xs = (_Float16*)(ws + 1 * SZ);     // f16
    float* abuf  = ws + 2 * SZ;
    float* oconv = ws + 3 * SZ;
    _Float16* khT = (_Float16*)(ws + 4 * SZ);
    _Float16* vhb = (_Float16*)(ws + 5 * SZ);
    float* pos   = ws + 6 * SZ;

    dim3 gqo(32, 12, 2);                // 32x32 tiles, 768 blocks
    gemm_wx<0><<<gqo, 256, 0, stream>>>(Wq, bq, x, qbuf);
    dwconv_kernel<<<768, 256, 0, stream>>>(qbuf, dww, dwb, oconv);
    offset_sample_once_kernel<<<dim3(32, 12), 256, 0, stream>>>(
        oconv, lng, lnb, pw, x, pos, xs);
    gemm_kv_fused<<<dim3(32, 12, 2), 256, 0, stream>>>(Wk, bk, Wv, bv, xs, khT, vhb);
    attn_mfma_kernel<<<dim3(64, 12), 256, 0, stream>>>(qbuf, khT, vhb, pos, rpe, abuf);
    gemm_wx<1><<<gqo, 256, 0, stream>>>(Wo, bo, abuf, (float*)d_out);
}

// Round 9
// 156.385 us; speedup vs baseline: 1.1255x; 1.1255x over previous
//
#include <hip/hip_runtime.h>
#include <hip/hip_fp16.h>
#include <math.h>
#include <string.h>

#define HH 32
#define WW 32
#define HWSZ 1024      // H*W
#define CC 384
#define NHEAD 12
#define NGROUP 6
#define HC 32
#define GC 64
#define NS 1024        // n_sample
#define ATTN_SCALE 0.17677669529663687f  // 32^-0.5

typedef _Float16 half8_t __attribute__((ext_vector_type(8)));
typedef _Float16 half4_t __attribute__((ext_vector_type(4)));
typedef _Float16 half2_t __attribute__((ext_vector_type(2)));
typedef float    f4_t    __attribute__((ext_vector_type(4)));

// ---------------------------------------------------------------------------
// R21 MFMA GEMM: Y = W·X + b. 32m x 32n tile, BK=32, grid (32,12,2)=768
// blocks -> 3 blocks/CU. Register prefetch of next K-tile between barriers.
// W pure f16; X pure f16 (XLO=0, q-proj) or f16 hi/lo (XLO=1, o-proj).
// ---------------------------------------------------------------------------
template<int XLO>
__global__ __launch_bounds__(256) void gemm_wx(
    const float* __restrict__ W, const float* __restrict__ bias,
    const float* __restrict__ X, float* __restrict__ Y)
{
    const int bz = blockIdx.z;
    const int tm = blockIdx.y * 32;
    const int tn = blockIdx.x * 32;
    const int tid = threadIdx.x;
    const int w = tid >> 6, lane = tid & 63;
    const int quad = lane >> 4, lcol = lane & 15;
    const int wr = w >> 1, wc = w & 1;       // wave's output quadrant

    __shared__ _Float16 sW[32][40];
    __shared__ _Float16 sX[32][40];
    __shared__ _Float16 sXl[XLO ? 32 : 1][40];

    const float* Xb = X + (size_t)bz * CC * 1024;
    float* Yb = Y + (size_t)bz * CC * 1024;

    const int m  = tid >> 3;
    const int j4 = (tid & 7) * 4;

    float4 wv = *(const float4*)&W[(size_t)(tm + m) * CC + j4];
    float4 xv = *(const float4*)&Xb[(size_t)m * 1024 + tn + j4];

    f4_t acc = {0.f, 0.f, 0.f, 0.f};

#pragma unroll 1
    for (int k0 = 0; k0 < CC; k0 += 32) {
        {
            half4_t hw; hw[0] = (_Float16)wv.x; hw[1] = (_Float16)wv.y;
            hw[2] = (_Float16)wv.z; hw[3] = (_Float16)wv.w;
            *(half4_t*)&sW[m][j4] = hw;
#pragma unroll
            for (int i = 0; i < 4; ++i) {
                float v = (i == 0) ? xv.x : (i == 1) ? xv.y : (i == 2) ? xv.z : xv.w;
                _Float16 h = (_Float16)v;
                sX[j4 + i][m] = h;
                if (XLO) sXl[j4 + i][m] = (_Float16)(v - (float)h);
            }
        }
        __syncthreads();

        if (k0 + 32 < CC) {
            wv = *(const float4*)&W[(size_t)(tm + m) * CC + k0 + 32 + j4];
            xv = *(const float4*)&Xb[(size_t)(k0 + 32 + m) * 1024 + tn + j4];
        }

        half8_t A = *(const half8_t*)&sW[wr * 16 + lcol][quad * 8];
        half8_t B = *(const half8_t*)&sX[wc * 16 + lcol][quad * 8];
        acc = __builtin_amdgcn_mfma_f32_16x16x32_f16(A, B, acc, 0, 0, 0);
        if (XLO) {
            half8_t Bl = *(const half8_t*)&sXl[wc * 16 + lcol][quad * 8];
            acc = __builtin_amdgcn_mfma_f32_16x16x32_f16(A, Bl, acc, 0, 0, 0);
        }
        __syncthreads();
    }

#pragma unroll
    for (int r = 0; r < 4; ++r) {
        int m0 = tm + wr * 16 + quad * 4 + r;
        Yb[(size_t)m0 * 1024 + tn + wc * 16 + lcol] = acc[r] + bias[m0];
    }
}

// ---------------------------------------------------------------------------
// R21 FUSED MFMA K+V projection, 32n tiles, grid (32,12,2)=768 blocks.
// ---------------------------------------------------------------------------
__global__ __launch_bounds__(256) void gemm_kv_fused(
    const float* __restrict__ Wk, const float* __restrict__ bk,
    const float* __restrict__ Wv, const float* __restrict__ bv,
    const _Float16* __restrict__ X,
    _Float16* __restrict__ khT, _Float16* __restrict__ vhb)
{
    const int bz = blockIdx.z;
    const int head = blockIdx.y;
    const int tm = head * 32;
    const int tn = blockIdx.x * 32;
    const int tid = threadIdx.x;
    const int w = tid >> 6, lane = tid & 63;
    const int quad = lane >> 4, lcol = lane & 15;
    const int bh = bz * 12 + head;
    const int nt = w & 1;

    __shared__ _Float16 sWk[32][40], sWv[32][40];
    __shared__ _Float16 sX[32][40];

    const _Float16* Xb = X + (size_t)bz * CC * 1024;

    const int m  = tid >> 3;
    const int j4 = (tid & 7) * 4;

    float4 wkv = *(const float4*)&Wk[(size_t)(tm + m) * CC + j4];
    float4 wvv = *(const float4*)&Wv[(size_t)(tm + m) * CC + j4];
    half4_t xh = *(const half4_t*)&Xb[(size_t)m * 1024 + tn + j4];

    f4_t a0 = {0.f, 0.f, 0.f, 0.f}, a1 = {0.f, 0.f, 0.f, 0.f};

#pragma unroll 1
    for (int k0 = 0; k0 < CC; k0 += 32) {
        {
            half4_t hk; hk[0] = (_Float16)wkv.x; hk[1] = (_Float16)wkv.y;
            hk[2] = (_Float16)wkv.z; hk[3] = (_Float16)wkv.w;
            half4_t hv; hv[0] = (_Float16)wvv.x; hv[1] = (_Float16)wvv.y;
            hv[2] = (_Float16)wvv.z; hv[3] = (_Float16)wvv.w;
            *(half4_t*)&sWk[m][j4] = hk;
            *(half4_t*)&sWv[m][j4] = hv;
#pragma unroll
            for (int i = 0; i < 4; ++i)
                sX[j4 + i][m] = xh[i];
        }
        __syncthreads();

        if (k0 + 32 < CC) {
            wkv = *(const float4*)&Wk[(size_t)(tm + m) * CC + k0 + 32 + j4];
            wvv = *(const float4*)&Wv[(size_t)(tm + m) * CC + k0 + 32 + j4];
            xh  = *(const half4_t*)&Xb[(size_t)(k0 + 32 + m) * 1024 + tn + j4];
        }

        half8_t Xa = *(const half8_t*)&sX[nt * 16 + lcol][quad * 8];
        if (w < 2) {
            half8_t K0 = *(const half8_t*)&sWk[lcol][quad * 8];
            half8_t K1 = *(const half8_t*)&sWk[16 + lcol][quad * 8];
            a0 = __builtin_amdgcn_mfma_f32_16x16x32_f16(Xa, K0, a0, 0, 0, 0);
            a1 = __builtin_amdgcn_mfma_f32_16x16x32_f16(Xa, K1, a1, 0, 0, 0);
        } else {
            half8_t V0 = *(const half8_t*)&sWv[lcol][quad * 8];
            half8_t V1 = *(const half8_t*)&sWv[16 + lcol][quad * 8];
            a0 = __builtin_amdgcn_mfma_f32_16x16x32_f16(V0, Xa, a0, 0, 0, 0);
            a1 = __builtin_amdgcn_mfma_f32_16x16x32_f16(V1, Xa, a1, 0, 0, 0);
        }
        __syncthreads();
    }

    if (w < 2) {
        float bk0 = bk[tm + lcol], bk1 = bk[tm + 16 + lcol];
#pragma unroll
        for (int r = 0; r < 4; ++r) {
            int n = tn + nt * 16 + quad * 4 + r;
            khT[((size_t)bh * 1024 + n) * 32 + lcol]      = (_Float16)(a0[r] + bk0);
            khT[((size_t)bh * 1024 + n) * 32 + 16 + lcol] = (_Float16)(a1[r] + bk1);
        }
    } else {
#pragma unroll
        for (int r = 0; r < 4; ++r) {
            int hc0 = quad * 4 + r;
            vhb[((size_t)bh * 32 + hc0) * 1024 + tn + nt * 16 + lcol] =
                (_Float16)(a0[r] + bv[tm + hc0]);
            vhb[((size_t)bh * 32 + hc0 + 16) * 1024 + tn + nt * 16 + lcol] =
                (_Float16)(a1[r] + bv[tm + hc0 + 16]);
        }
    }
}

// ---------------------------------------------------------------------------
// Depthwise 7x7 conv, zero pad 3 (unchanged).
// ---------------------------------------------------------------------------
__global__ __launch_bounds__(256) void dwconv_kernel(
    const float* __restrict__ q, const float* __restrict__ dww,
    const float* __restrict__ dwb, float* __restrict__ oconv)
{
    const int bc = blockIdx.x;
    const int bg = bc >> 6, c = bc & 63;
    const int b = bg / 6, g = bg % 6;
    const float* plane = q + ((size_t)b * CC + g * 64 + c) * 1024;

    __shared__ float sp[1024];
    __shared__ float sw[49];
    const int tid = threadIdx.x;
    for (int i = tid; i < 1024; i += 256) sp[i] = plane[i];
    if (tid < 49) sw[tid] = dww[c * 49 + tid];
    __syncthreads();

    const float bias = dwb[c];
    for (int i = tid; i < 1024; i += 256) {
        int y = i >> 5, x = i & 31;
        float s = 0.f;
#pragma unroll
        for (int ky = 0; ky < 7; ++ky) {
            int yy = y + ky - 3;
            if (yy < 0 || yy > 31) continue;
#pragma unroll
            for (int kx = 0; kx < 7; ++kx) {
                int xx = x + kx - 3;
                if (xx < 0 || xx > 31) continue;
                s += sp[yy * 32 + xx] * sw[ky * 7 + kx];
            }
        }
        oconv[(size_t)bc * 1024 + i] = s + bias;
    }
}

// ---------------------------------------------------------------------------
// R22: LN + GELU + pw + tanh once per pixel -> pos, then gather all 64 ch
// -> xs (f16). 32 px x 8 ch-groups per block, grid (32,12)=384 blocks.
// ---------------------------------------------------------------------------
__global__ __launch_bounds__(256) void offset_sample_once_kernel(
    const float* __restrict__ oconv, const float* __restrict__ lng,
    const float* __restrict__ lnb, const float* __restrict__ pw,
    const float* __restrict__ x, float* __restrict__ pos,
    _Float16* __restrict__ xs)
{
    const int bg = blockIdx.y;
    const int px0 = blockIdx.x * 32;
    const int t = threadIdx.x;
    const int cg = t >> 5;          // 0..7 channel group (8 ch each)
    const int pl = t & 31;          // 0..31 pixel
    const int px = px0 + pl;
    const int b = bg / 6, g = bg % 6;

    __shared__ float red[8][32];
    __shared__ float spos[32][2];

    const float* base = oconv + ((size_t)bg * 64 + cg * 8) * 1024 + px;
    float col[8];
    float s = 0.f;
#pragma unroll
    for (int i = 0; i < 8; ++i) { col[i] = base[(size_t)i * 1024]; s += col[i]; }
    red[cg][pl] = s;
    __syncthreads();
    float mu = 0.f;
#pragma unroll
    for (int j = 0; j < 8; ++j) mu += red[j][pl];
    mu *= (1.f / 64.f);
    float v = 0.f;
#pragma unroll
    for (int i = 0; i < 8; ++i) { float d = col[i] - mu; v += d * d; }
    __syncthreads();
    red[cg][pl] = v;
    __syncthreads();
    float vs = 0.f;
#pragma unroll
    for (int j = 0; j < 8; ++j) vs += red[j][pl];
    float inv = rsqrtf(vs * (1.f / 64.f) + 1e-5f);

    float oy = 0.f, ox = 0.f;
#pragma unroll
    for (int i = 0; i < 8; ++i) {
        int c = cg * 8 + i;
        float val = (col[i] - mu) * inv * lng[c] + lnb[c];
        float gl = 0.5f * val * (1.f + erff(val * 0.70710678118654752440f));
        oy += gl * pw[c];
        ox += gl * pw[64 + c];
    }
    __syncthreads();
    red[cg][pl] = oy;
    __syncthreads();
    float oyt = 0.f;
#pragma unroll
    for (int j = 0; j < 8; ++j) oyt += red[j][pl];
    __syncthreads();
    red[cg][pl] = ox;
    __syncthreads();
    if (cg == 0) {
        float oxt = 0.f;
#pragma unroll
        for (int j = 0; j < 8; ++j) oxt += red[j][pl];
        float offy = tanhf(oyt) * (2.0f / 32.0f);
        float offx = tanhf(oxt) * (2.0f / 32.0f);
        int y = px >> 5, xx = px & 31;
        float ry = ((y + 0.5f) / 32.f) * 2.f - 1.f;
        float rx = ((xx + 0.5f) / 32.f) * 2.f - 1.f;
        float pyv = offy + ry, pxv = offx + rx;
        spos[pl][0] = pyv; spos[pl][1] = pxv;
        pos[((size_t)bg * 1024 + px) * 2 + 0] = pyv;
        pos[((size_t)bg * 1024 + px) * 2 + 1] = pxv;
    }
    __syncthreads();

    float py = spos[pl][0], pxv = spos[pl][1];
    float gx = (pxv + 1.f) * 0.5f * 31.f;
    float gy = (py + 1.f) * 0.5f * 31.f;
    float x0f = floorf(gx), y0f = floorf(gy);
    float wx = gx - x0f, wy = gy - y0f;
    int x0 = (int)x0f, y0 = (int)y0f;
    float vx0 = ((unsigned)x0 <= 31u) ? 1.f : 0.f;
    float vx1 = ((unsigned)(x0 + 1) <= 31u) ? 1.f : 0.f;
    float vy0 = ((unsigned)y0 <= 31u) ? 1.f : 0.f;
    float vy1 = ((unsigned)(y0 + 1) <= 31u) ? 1.f : 0.f;
    float w00 = (1.f - wx) * (1.f - wy) * vx0 * vy0;
    float w01 = wx * (1.f - wy) * vx1 * vy0;
    float w10 = (1.f - wx) * wy * vx0 * vy1;
    float w11 = wx * wy * vx1 * vy1;
    int xc0 = min(max(x0, 0), 31), xc1 = min(max(x0 + 1, 0), 31);
    int yc0 = min(max(y0, 0), 31), yc1 = min(max(y0 + 1, 0), 31);
    int i00 = yc0 * 32 + xc0, i01 = yc0 * 32 + xc1;
    int i10 = yc1 * 32 + xc0, i11 = yc1 * 32 + xc1;

    const float* xg = x + ((size_t)b * CC + g * 64) * 1024;
    _Float16* xso = xs + ((size_t)b * CC + g * 64) * 1024 + px;
#pragma unroll
    for (int i = 0; i < 8; ++i) {
        int c = cg * 8 + i;
        const float* plane = xg + (size_t)c * 1024;
        xso[(size_t)c * 1024] =
            (_Float16)(plane[i00] * w00 + plane[i01] * w01
                     + plane[i10] * w10 + plane[i11] * w11);
    }
}

// ---------------------------------------------------------------------------
// MFMA flash attention, TWO HEADS PER BLOCK. R24 = R22 hot loop (100 VGPR,
// no spills) + R23's packed 8-byte geometry ONLY:
//  - sgeo[key] = {f32 u, f16 wy | i16 iy} -> one ds_read_b64 per key;
//    LDS 42112 -> 38016 B < 40KB -> 4 blocks/CU LDS-limited (was 3).
//  - NO __launch_bounds__ min-waves floor (R23's (256,4) capped VGPR at 64
//    -> 84MB scratch spill traffic, attn 44.7 -> 52us REGRESSION).
// ---------------------------------------------------------------------------
__global__ __launch_bounds__(256) void attn_mfma_kernel(
    const float* __restrict__ q, const _Float16* __restrict__ khT,
    const _Float16* __restrict__ vhb, const float* __restrict__ pos,
    const float* __restrict__ rpe, float* __restrict__ out)
{
    const int bgp = blockIdx.y;            // 0..11 = (b, g)
    const int b = bgp / 6, g = bgp % 6;
    const int h0 = g * 2;
    const int bh0 = b * 12 + h0, bh1 = bh0 + 1;
    const int mblk = blockIdx.x * 16;
    const int tid = threadIdx.x;
    const int w = tid >> 6, lane = tid & 63;
    const int quad = lane >> 4, lcol = lane & 15;

    __shared__ __align__(16) char smem[38016];
    half2_t*  srpeA = (half2_t*)smem;                        // 2205 x {h0,h1}
    _Float16* sqh   = (_Float16*)(smem + 8832);              // 2048B
    _Float16* spw   = (_Float16*)(smem + 10880) + w * 2304;  // P slabs
    float*    comb0 = (float*)(smem + 10880);                // alias P slabs
    float*    comb1 = (float*)(smem + 20096);
    float*    cml0  = (float*)(smem + 29312);
    float*    cml1  = (float*)(smem + 29568);
    float2*   sgeo  = (float2*)(smem + 29824);               // packed geometry

    const float qyw = (((mblk >> 5) + 0.5f) * (1.f / 32.f)) * 2.f - 1.f;
    int r0; {
        float gy_lo = (qyw - 1.03125f) * 15.5f + 31.f;
        r0 = (int)floorf(gy_lo);
        r0 = min(max(r0, 0), 28);
    }

    {   // stage both heads' RPE window, head-interleaved (single table)
        const float* rp0 = rpe + (size_t)h0 * 3969;
        const float* rp1 = rp0 + 3969;
        for (int i = tid; i < 35 * 63; i += 256) {
            int y = i / 63, xx = i - y * 63;
            int gi = (r0 + y) * 63 + xx;
            half2_t hA; hA[0] = (_Float16)rp0[gi]; hA[1] = (_Float16)rp1[gi];
            srpeA[i] = hA;
        }
    }
    {   // stage q (pre-scaled by ATTN_SCALE) for both heads: [head][m][hc]
        const float* qb = q + ((size_t)b * CC + h0 * 32) * 1024 + mblk;
        for (int i = tid; i < 1024; i += 256) {
            int hh = i >> 9, rem = i & 511;
            int hc = rem >> 4, m = rem & 15;
            sqh[hh * 512 + m * 32 + hc] =
                (_Float16)(qb[(size_t)(hh * 32 + hc) * 1024 + m] * ATTN_SCALE);
        }
    }
    {   // per-key packed geometry: {u = 31 - px*15.5, wy f16 | iy i16}
        const float2* pgv = (const float2*)(pos + (size_t)bgp * 2048);
        for (int i = tid; i < 1024; i += 256) {
            float2 pp = pgv[i];
            float gy = (qyw - pp.x) * 15.5f + 31.f;
            float y0f = floorf(gy);
            _Float16 wyh = (_Float16)(gy - y0f);
            int iy = ((int)y0f - r0) * 63;
            unsigned short wyb;
            __builtin_memcpy(&wyb, &wyh, 2);
            unsigned pk = ((unsigned)(unsigned short)(short)iy << 16) | wyb;
            sgeo[i] = make_float2(31.f - pp.y * 15.5f, __uint_as_float(pk));
        }
    }
    __syncthreads();

    half8_t qf0 = *(const half8_t*)&sqh[lcol * 32 + quad * 8];
    half8_t qf1 = *(const half8_t*)&sqh[512 + lcol * 32 + quad * 8];
    const float qxs = ((mblk & 31) + lcol + 0.5f) * 0.96875f - 15.5f;  // qx*15.5

    const _Float16* khb0 = khT + (size_t)bh0 * 1024 * 32;
    const _Float16* khb1 = khT + (size_t)bh1 * 1024 * 32;
    const _Float16* vhh0 = vhb + (size_t)bh0 * 32 * 1024;
    const _Float16* vhh1 = vhb + (size_t)bh1 * 32 * 1024;

    f4_t o00 = {0.f, 0.f, 0.f, 0.f}, o01 = {0.f, 0.f, 0.f, 0.f};
    f4_t o10 = {0.f, 0.f, 0.f, 0.f}, o11 = {0.f, 0.f, 0.f, 0.f};
    float lsum0 = 0.f, lsum1 = 0.f;

    half8_t kA0[4], kA1[4], kB0[4], kB1[4];

    auto loadK = [&](half8_t* d0, half8_t* d1, int cc) {
        int nn = w * 256 + cc * 64;
#pragma unroll
        for (int t = 0; t < 4; ++t) {
            size_t off = (size_t)(nn + t * 16 + lcol) * 32 + quad * 8;
            d0[t] = *(const half8_t*)&khb0[off];
            d1[t] = *(const half8_t*)&khb1[off];
        }
    };

    auto computeC = [&](const half8_t* kh0, const half8_t* kh1, int c) {
        const int n0 = w * 256 + c * 64;

        f4_t S0[4], S1[4];
#pragma unroll
        for (int t = 0; t < 4; ++t) {
            f4_t s0 = {0.f, 0.f, 0.f, 0.f}, s1 = {0.f, 0.f, 0.f, 0.f};
            s0 = __builtin_amdgcn_mfma_f32_16x16x32_f16(kh0[t], qf0, s0, 0, 0, 0);
            s1 = __builtin_amdgcn_mfma_f32_16x16x32_f16(kh1[t], qf1, s1, 0, 0, 0);
#pragma unroll
            for (int r = 0; r < 4; ++r) {
                int key = n0 + t * 16 + quad * 4 + r;
                float2 gg = sgeo[key];           // one b64 broadcast read
                float gx = qxs + gg.x;
                float x0f = floorf(gx);
                unsigned pk = __float_as_uint(gg.y);
                int i00 = (int)(short)(pk >> 16) + (int)x0f;
                half2_t a0 = srpeA[i00];
                half2_t b0 = srpeA[i00 + 1];
                half2_t a1 = srpeA[i00 + 63];
                half2_t b1 = srpeA[i00 + 64];
                _Float16 wxs = (_Float16)(gx - x0f);
                _Float16 wys;
                unsigned short wyb = (unsigned short)(pk & 0xFFFFu);
                __builtin_memcpy(&wys, &wyb, 2);
                half2_t wxh; wxh[0] = wxs; wxh[1] = wxs;
                half2_t wyh; wyh[0] = wys; wyh[1] = wys;
                half2_t top = a0 + (b0 - a0) * wxh;
                half2_t bot = a1 + (b1 - a1) * wxh;
                half2_t res = top + (bot - top) * wyh;
                s0[r] = s0[r] + (float)res[0];    // scale pre-folded into q
                s1[r] = s1[r] + (float)res[1];
            }
            S0[t] = s0; S1[t] = s1;
        }

        // prefetch V for head0 (covers exp-section latency)
        half8_t vv00[2], vv01[2];
#pragma unroll
        for (int kp = 0; kp < 2; ++kp) {
            int nb = n0 + kp * 32 + quad * 8;
            vv00[kp] = *(const half8_t*)&vhh0[(size_t)lcol * 1024 + nb];
            vv01[kp] = *(const half8_t*)&vhh0[(size_t)(16 + lcol) * 1024 + nb];
        }

        // fixed-shift exp + P stores for both heads
#pragma unroll
        for (int t = 0; t < 4; ++t) {
            float p0 = __expf(S0[t][0]), p1 = __expf(S0[t][1]);
            float p2 = __expf(S0[t][2]), p3 = __expf(S0[t][3]);
            lsum0 += (p0 + p1) + (p2 + p3);
            half4_t h;
            h[0] = (_Float16)p0; h[1] = (_Float16)p1;
            h[2] = (_Float16)p2; h[3] = (_Float16)p3;
            *(half4_t*)&spw[lcol * 72 + t * 16 + quad * 4] = h;
            float r0e = __expf(S1[t][0]), r1e = __expf(S1[t][1]);
            float r2e = __expf(S1[t][2]), r3e = __expf(S1[t][3]);
            lsum1 += (r0e + r1e) + (r2e + r3e);
            half4_t h1;
            h1[0] = (_Float16)r0e; h1[1] = (_Float16)r1e;
            h1[2] = (_Float16)r2e; h1[3] = (_Float16)r3e;
            *(half4_t*)&spw[1152 + lcol * 72 + t * 16 + quad * 4] = h1;
        }

        // PV head0 (wave-internal LDS read-back; no barrier)
#pragma unroll
        for (int kp = 0; kp < 2; ++kp) {
            half8_t pb = *(const half8_t*)&spw[lcol * 72 + kp * 32 + quad * 8];
            o00 = __builtin_amdgcn_mfma_f32_16x16x32_f16(vv00[kp], pb, o00, 0, 0, 0);
            o01 = __builtin_amdgcn_mfma_f32_16x16x32_f16(vv01[kp], pb, o01, 0, 0, 0);
        }
        // PV head1 (V loaded JIT)
#pragma unroll
        for (int kp = 0; kp < 2; ++kp) {
            int nb = n0 + kp * 32 + quad * 8;
            half8_t v0 = *(const half8_t*)&vhh1[(size_t)lcol * 1024 + nb];
            half8_t v1 = *(const half8_t*)&vhh1[(size_t)(16 + lcol) * 1024 + nb];
            half8_t pb = *(const half8_t*)&spw[1152 + lcol * 72 + kp * 32 + quad * 8];
            o10 = __builtin_amdgcn_mfma_f32_16x16x32_f16(v0, pb, o10, 0, 0, 0);
            o11 = __builtin_amdgcn_mfma_f32_16x16x32_f16(v1, pb, o11, 0, 0, 0);
        }
    };

    loadK(kA0, kA1, 0);
#pragma unroll 1
    for (int it = 0; it < 2; ++it) {
        int c = it * 2;
        loadK(kB0, kB1, c + 1);          // prefetch c+1 before computing c
        computeC(kA0, kA1, c);
        if (it == 0) loadK(kA0, kA1, c + 2);
        computeC(kB0, kB1, c + 1);
    }

    lsum0 += __shfl_xor(lsum0, 16); lsum0 += __shfl_xor(lsum0, 32);
    lsum1 += __shfl_xor(lsum1, 16); lsum1 += __shfl_xor(lsum1, 32);

    __syncthreads();   // all waves done with P slabs -> alias as comb0/comb1

    *(f4_t*)&comb0[(w * 16 + lcol) * 36 + quad * 4]      = o00;
    *(f4_t*)&comb0[(w * 16 + lcol) * 36 + 16 + quad * 4] = o01;
    *(f4_t*)&comb1[(w * 16 + lcol) * 36 + quad * 4]      = o10;
    *(f4_t*)&comb1[(w * 16 + lcol) * 36 + 16 + quad * 4] = o11;
    if (quad == 0) {
        cml0[w * 16 + lcol] = lsum0;
        cml1[w * 16 + lcol] = lsum1;
    }
    __syncthreads();

#pragma unroll
    for (int i = 0; i < 2; ++i) {
        int idx = tid + i * 256;
        int qq = idx >> 5, hc = idx & 31;
        {
            float L = cml0[qq] + cml0[16 + qq] + cml0[32 + qq] + cml0[48 + qq];
            float o = comb0[(0 * 16 + qq) * 36 + hc]
                    + comb0[(1 * 16 + qq) * 36 + hc]
                    + comb0[(2 * 16 + qq) * 36 + hc]
                    + comb0[(3 * 16 + qq) * 36 + hc];
            out[((size_t)b * CC + h0 * 32 + hc) * 1024 + mblk + qq] = o / L;
        }
        {
            float L = cml1[qq] + cml1[16 + qq] + cml1[32 + qq] + cml1[48 + qq];
            float o = comb1[(0 * 16 + qq) * 36 + hc]
                    + comb1[(1 * 16 + qq) * 36 + hc]
                    + comb1[(2 * 16 + qq) * 36 + hc]
                    + comb1[(3 * 16 + qq) * 36 + hc];
            out[((size_t)b * CC + (h0 + 1) * 32 + hc) * 1024 + mblk + qq] = o / L;
        }
    }
}

// ---------------------------------------------------------------------------
extern "C" void kernel_launch(void* const* d_in, const int* in_sizes, int n_in,
                              void* d_out, int out_size, void* d_ws, size_t ws_size,
                              hipStream_t stream) {
    const float* x   = (const float*)d_in[0];
    const float* Wq  = (const float*)d_in[1];
    const float* bq  = (const float*)d_in[2];
    const float* Wk  = (const float*)d_in[3];
    const float* bk  = (const float*)d_in[4];
    const float* Wv  = (const float*)d_in[5];
    const float* bv  = (const float*)d_in[6];
    const float* Wo  = (const float*)d_in[7];
    const float* bo  = (const float*)d_in[8];
    const float* dww = (const float*)d_in[9];
    const float* dwb = (const float*)d_in[10];
    const float* lng = (const float*)d_in[11];
    const float* lnb = (const float*)d_in[12];
    const float* pw  = (const float*)d_in[13];
    const float* rpe = (const float*)d_in[14];

    float* ws = (float*)d_ws;
    const size_t SZ = 786432;           // 2*384*1024 floats
    float* qbuf  = ws;
    _Float16* xs = (_Float16*)(ws + 1 * SZ);     // f16
    float* abuf  = ws + 2 * SZ;
    float* oconv = ws + 3 * SZ;
    _Float16* khT = (_Float16*)(ws + 4 * SZ);
    _Float16* vhb = (_Float16*)(ws + 5 * SZ);
    float* pos   = ws + 6 * SZ;

    dim3 gqo(32, 12, 2);                // 32x32 tiles, 768 blocks
    gemm_wx<0><<<gqo, 256, 0, stream>>>(Wq, bq, x, qbuf);
    dwconv_kernel<<<768, 256, 0, stream>>>(qbuf, dww, dwb, oconv);
    offset_sample_once_kernel<<<dim3(32, 12), 256, 0, stream>>>(
        oconv, lng, lnb, pw, x, pos, xs);
    gemm_kv_fused<<<dim3(32, 12, 2), 256, 0, stream>>>(Wk, bk, Wv, bv, xs, khT, vhb);
    attn_mfma_kernel<<<dim3(64, 12), 256, 0, stream>>>(qbuf, khT, vhb, pos, rpe, abuf);
    gemm_wx<1><<<gqo, 256, 0, stream>>>(Wo, bo, abuf, (float*)d_out);
}